// Round 6
// baseline (27.244 us; speedup 1.0000x reference)
//
#include <hip/hip_runtime.h>
#include <math.h>

#define RES 2048
#define NB  256

typedef _Float16 f16;
typedef _Float16 f16x8 __attribute__((ext_vector_type(8)));
typedef float    f32x16 __attribute__((ext_vector_type(16)));

#define AS1 __attribute__((address_space(1)))
#define AS3 __attribute__((address_space(3)))

__device__ __forceinline__ void g2l16(const void* g, void* l) {
    // async 16B/lane global->LDS; LDS dest = wave-uniform base + lane*16
    __builtin_amdgcn_global_load_lds((const AS1 void*)g, (AS3 void*)l, 16, 0, 0);
}

__device__ __forceinline__ f16x8 neg8(f16x8 v) {
    union { f16x8 h; unsigned int u[4]; } x;
    x.h = v;
    #pragma unroll
    for (int i = 0; i < 4; ++i) x.u[i] ^= 0x80008000u;
    return x.h;
}

// ---------------------------------------------------------------------------
// Kernel 1: per-beam, per-axis complex tables, [pos][beam] layout, fp16.
//   A(i,b) = (re + i*im) * exp(-(x_i-x0)^2/s^2) * exp(i*kx*x_i)   (M side)
//   B(j,b) =               exp(-(y_j-y0)^2/s^2) * exp(i*ky*y_j)   (N side)
// Per-beam params computed ONCE per block into LDS; fast intrinsics.
// ---------------------------------------------------------------------------
#define POSPB 8

__global__ __launch_bounds__(NB) void beam_tables_f16(
    const float* __restrict__ theta, const float* __restrict__ reA,
    const float* __restrict__ imA, const float* __restrict__ x0A,
    const float* __restrict__ y0A, const float* __restrict__ lsA,
    const float* __restrict__ X, const float* __restrict__ Y,
    f16* __restrict__ ARe, f16* __restrict__ AIm,
    f16* __restrict__ BRe, f16* __restrict__ BIm)
{
    __shared__ float skx[NB], sky[NB], sre[NB], sim[NB], spx[NB], spy[NB], sis2[NB];
    const int b = threadIdx.x;
    {
        float s, c;
        __sincosf(theta[b], &s, &c);
        skx[b] = 50.0f * c;
        sky[b] = 50.0f * s;
        const float sig = __expf(lsA[b]) + 0.001f;
        sis2[b] = 1.0f / (sig * sig);
        sre[b] = reA[b]; sim[b] = imA[b];
        spx[b] = x0A[b]; spy[b] = y0A[b];
    }
    __syncthreads();

    const float kx = skx[b], ky = sky[b];
    const float re = sre[b], im = sim[b];
    const float px = spx[b], py = spy[b];
    const float is2 = sis2[b];

    #pragma unroll
    for (int ii = 0; ii < POSPB; ++ii) {
        const int i = blockIdx.x * POSPB + ii;
        const float xv = X[(size_t)i * RES];  // X[i][0] = x_i (indexing='ij')
        const float yv = Y[i];                // Y[0][j] = y_j
        float sx, cx, sy, cy;
        __sincosf(kx * xv, &sx, &cx);
        __sincosf(ky * yv, &sy, &cy);
        const float dx = xv - px, dy = yv - py;
        const float ex = __expf(-dx * dx * is2);
        const float ey = __expf(-dy * dy * is2);
        const int o = i * NB + b;
        ARe[o] = (f16)(ex * (re * cx - im * sx));
        AIm[o] = (f16)(ex * (re * sx + im * cx));
        BRe[o] = (f16)(ey * cy);
        BIm[o] = (f16)(ey * sy);
    }
}

// ---------------------------------------------------------------------------
// Kernel 2: complex GEMM on matrix cores.  E[i,j] = sum_b A(i,b)*B(j,b).
// mfma_f32_32x32x16_f16, BM=BN=128, BK=16, 512 threads = 8 waves (2Mx4N),
// wave tile 64x32 -> 2 C-tiles (Re+Im) = 64 acc VGPR (low pressure,
// 2 waves/SIMD for TLP so barrier/vmcnt drains are hidden by the other wave).
// 4 LDS planes {ARe,AIm,BRe,BIm}; BIm negated in-register (exact).
// LDS: [2 buf][4 planes][128 rows][16 f16] = 32 KB, 2-phase double-buffer
// via global_load_lds (zero staging VGPRs), one barrier per k-tile.
// Per k-tile per wave: 6 ds_read_b128 + 8 MFMA; frag reads are fully
// contiguous 1024B regions (BK=16 -> 32B rows) = conflict-free.
// ---------------------------------------------------------------------------
#define BM 128
#define BN 128
#define BK 16
#define NKT (NB / BK)          // 16
#define PL  (BM * BK)          // elements per plane (2048)
#define BUFSTRIDE (4 * PL)

__global__ __launch_bounds__(512) void ewald_mfma(
    const f16* __restrict__ ARe, const f16* __restrict__ AIm,
    const f16* __restrict__ BRe, const f16* __restrict__ BIm,
    float* __restrict__ out)
{
    __shared__ f16 sm[2][4][BM][BK];
    f16* const smBase = &sm[0][0][0][0];

    const int t    = threadIdx.x;
    const int lane = t & 63;
    const int wave = t >> 6;       // 0..7
    const int wm   = wave >> 2;    // 0..1 -> M offset 64
    const int wn   = wave & 3;     // 0..3 -> N offset 32
    const int la   = lane & 31;
    const int lg   = lane >> 5;

    // XCD-aware swizzle (256 blocks, 8 XCDs -> 32 contiguous per XCD)
    const int flat = blockIdx.x;
    const int swz  = (flat & 7) * 32 + (flat >> 3);
    const int m0   = (swz >> 4) * BM;
    const int n0   = (swz & 15) * BN;

    // ---- staging map: 16 wave-loads (1 KB each) per k-tile, 2 per wave ----
    // q = wave + 8*j; plane p = q>>2 in {ARe,AIm,BRe,BIm}; chunk c = q&3
    // covers rows c*32..c*32+31; lane l -> row c*32 + (l>>1), k-half l&1.
    const f16* gsrc[2];
    int ldso[2];
    #pragma unroll
    for (int j = 0; j < 2; ++j) {
        const int q = wave + 8 * j;
        const int p = q >> 2;
        const int c = q & 3;
        const f16* tp = (p == 0) ? ARe : (p == 1) ? AIm : (p == 2) ? BRe : BIm;
        const int rowbase = ((p < 2) ? m0 : n0) + c * 32 + (lane >> 1);
        gsrc[j] = tp + (size_t)rowbase * NB + (lane & 1) * 8;
        ldso[j] = p * PL + c * 512;
    }

    #define STAGE(boff, kt)                                                   \
    do {                                                                      \
        g2l16(gsrc[0] + (kt) * BK, smBase + (boff) + ldso[0]);                \
        g2l16(gsrc[1] + (kt) * BK, smBase + (boff) + ldso[1]);                \
    } while (0)

    // ---- fragment LDS element-offsets (within one buffer) ----
    const int offAR0 = 0 * PL + (wm * 64 +  0 + la) * BK + lg * 8;
    const int offAR1 = 0 * PL + (wm * 64 + 32 + la) * BK + lg * 8;
    const int offAI0 = 1 * PL + (wm * 64 +  0 + la) * BK + lg * 8;
    const int offAI1 = 1 * PL + (wm * 64 + 32 + la) * BK + lg * 8;
    const int offBR  = 2 * PL + (wn * 32 + la) * BK + lg * 8;
    const int offBI  = 3 * PL + (wn * 32 + la) * BK + lg * 8;

    f32x16 accRe0 = (f32x16)0.0f, accIm0 = (f32x16)0.0f;
    f32x16 accRe1 = (f32x16)0.0f, accIm1 = (f32x16)0.0f;

    // ---- prologue ----
    STAGE(0, 0);
    __syncthreads();

    for (int kt = 0; kt < NKT; ++kt) {
        const int boff = (kt & 1) * BUFSTRIDE;
        if (kt + 1 < NKT)
            STAGE(((kt + 1) & 1) * BUFSTRIDE, kt + 1);

        const f16* s = smBase + boff;
        const f16x8 aR0 = *(const f16x8*)(s + offAR0);
        const f16x8 aR1 = *(const f16x8*)(s + offAR1);
        const f16x8 aI0 = *(const f16x8*)(s + offAI0);
        const f16x8 aI1 = *(const f16x8*)(s + offAI1);
        const f16x8 bR  = *(const f16x8*)(s + offBR);
        const f16x8 bI  = *(const f16x8*)(s + offBI);
        const f16x8 bN  = neg8(bI);

        accRe0 = __builtin_amdgcn_mfma_f32_32x32x16_f16(aR0, bR, accRe0, 0, 0, 0);
        accRe0 = __builtin_amdgcn_mfma_f32_32x32x16_f16(aI0, bN, accRe0, 0, 0, 0);
        accIm0 = __builtin_amdgcn_mfma_f32_32x32x16_f16(aR0, bI, accIm0, 0, 0, 0);
        accIm0 = __builtin_amdgcn_mfma_f32_32x32x16_f16(aI0, bR, accIm0, 0, 0, 0);
        accRe1 = __builtin_amdgcn_mfma_f32_32x32x16_f16(aR1, bR, accRe1, 0, 0, 0);
        accRe1 = __builtin_amdgcn_mfma_f32_32x32x16_f16(aI1, bN, accRe1, 0, 0, 0);
        accIm1 = __builtin_amdgcn_mfma_f32_32x32x16_f16(aR1, bI, accIm1, 0, 0, 0);
        accIm1 = __builtin_amdgcn_mfma_f32_32x32x16_f16(aI1, bR, accIm1, 0, 0, 0);

        __syncthreads();
    }

    // ---- epilogue: out = Re^2 + Im^2 ----
    // C/D layout (32x32): col = lane&31, row = (reg&3) + 8*(reg>>2) + 4*(lane>>5)
    const int gn = n0 + wn * 32 + la;
    const int gmBase = m0 + wm * 64;
    #pragma unroll
    for (int r = 0; r < 16; ++r) {
        const int row = (r & 3) + 8 * (r >> 2) + 4 * lg;
        const float er = accRe0[r], ei = accIm0[r];
        out[(size_t)(gmBase + row) * RES + gn] = er * er + ei * ei;
    }
    #pragma unroll
    for (int r = 0; r < 16; ++r) {
        const int row = (r & 3) + 8 * (r >> 2) + 4 * lg;
        const float er = accRe1[r], ei = accIm1[r];
        out[(size_t)(gmBase + 32 + row) * RES + gn] = er * er + ei * ei;
    }
    #undef STAGE
}

// ---------------------------------------------------------------------------
// Fallback: direct brute force (only used if ws_size too small).
// ---------------------------------------------------------------------------
__global__ __launch_bounds__(256) void ewald_direct(
    const float* __restrict__ theta, const float* __restrict__ reA,
    const float* __restrict__ imA, const float* __restrict__ x0A,
    const float* __restrict__ y0A, const float* __restrict__ lsA,
    const float* __restrict__ X, const float* __restrict__ Y,
    float* __restrict__ out)
{
    __shared__ float kxs[NB], kys[NB], res[NB], ims[NB], pxs[NB], pys[NB], is2s[NB];
    const int t = threadIdx.x;
    if (t < NB) {
        const float th  = theta[t];
        const float sig = expf(lsA[t]) + 0.001f;
        kxs[t] = 50.0f * cosf(th);
        kys[t] = 50.0f * sinf(th);
        res[t] = reA[t];
        ims[t] = imA[t];
        pxs[t] = x0A[t];
        pys[t] = y0A[t];
        is2s[t] = 1.0f / (sig * sig);
    }
    __syncthreads();

    const size_t npix = (size_t)RES * RES;
    for (size_t idx = (size_t)blockIdx.x * blockDim.x + t; idx < npix;
         idx += (size_t)gridDim.x * blockDim.x) {
        const float xv = X[idx], yv = Y[idx];
        float er = 0.f, ei = 0.f;
        for (int b = 0; b < NB; ++b) {
            const float dx = xv - pxs[b], dy = yv - pys[b];
            const float env = __expf(-(dx * dx + dy * dy) * is2s[b]);
            const float ph = kxs[b] * xv + kys[b] * yv;
            float s, c;
            __sincosf(ph, &s, &c);
            er += env * (res[b] * c - ims[b] * s);
            ei += env * (res[b] * s + ims[b] * c);
        }
        out[idx] = er * er + ei * ei;
    }
}

// ---------------------------------------------------------------------------
extern "C" void kernel_launch(void* const* d_in, const int* in_sizes, int n_in,
                              void* d_out, int out_size, void* d_ws, size_t ws_size,
                              hipStream_t stream) {
    const float* theta = (const float*)d_in[0];
    const float* reA   = (const float*)d_in[1];
    const float* imA   = (const float*)d_in[2];
    const float* x0A   = (const float*)d_in[3];
    const float* y0A   = (const float*)d_in[4];
    const float* lsA   = (const float*)d_in[5];
    const float* X     = (const float*)d_in[6];
    const float* Y     = (const float*)d_in[7];
    float* out = (float*)d_out;

    const size_t tbl  = (size_t)RES * NB;          // elements per plane
    const size_t need = 4 * tbl * sizeof(f16);     // 4 MB

    if (ws_size >= need) {
        f16* ARe = (f16*)d_ws;
        f16* AIm = ARe + tbl;
        f16* BRe = AIm + tbl;
        f16* BIm = BRe + tbl;

        beam_tables_f16<<<RES / POSPB, NB, 0, stream>>>(
            theta, reA, imA, x0A, y0A, lsA, X, Y, ARe, AIm, BRe, BIm);

        ewald_mfma<<<256, 512, 0, stream>>>(ARe, AIm, BRe, BIm, out);
    } else {
        ewald_direct<<<2048, 256, 0, stream>>>(theta, reA, imA, x0A, y0A, lsA,
                                               X, Y, out);
    }
}

// Round 7
// 24.576 us; speedup vs baseline: 1.1085x; 1.1085x over previous
//
#include <hip/hip_runtime.h>
#include <math.h>

#define RES 2048
#define NB  256

typedef _Float16 f16;
typedef _Float16 f16x8 __attribute__((ext_vector_type(8)));
typedef float    f32x16 __attribute__((ext_vector_type(16)));

#define BM 128
#define BN 128
#define BK 16
#define NKT (NB / BK)      // 16 k-tiles
#define PL  (BM * BK)      // elements per plane (2048)

__device__ __forceinline__ f16x8 neg8(f16x8 v) {
    union { f16x8 h; unsigned int u[4]; } x;
    x.h = v;
    #pragma unroll
    for (int i = 0; i < 4; ++i) x.u[i] ^= 0x80008000u;
    return x.h;
}

// ---------------------------------------------------------------------------
// Fully fused kernel: no global staging, no workspace, one launch.
// E[i,j] = sum_b A(i,b)*B(j,b)  (complex),  out = |E|^2, with
//   A(i,b) = (re+i*im)*exp(-(x_i-x0)^2/s^2)*exp(i*kx*x_i)
//   B(j,b) =            exp(-(y_j-y0)^2/s^2)*exp(i*ky*y_j)
// Each block (128x128 output tile) recomputes its own A/B panels per k-tile
// of 16 beams DIRECTLY INTO LDS (fp16), then consumes them with
// mfma_f32_32x32x16_f16. Double-buffered: MFMAs for tile t issue into the
// matrix pipe, then the VALU evaluates tile t+1 (separate pipes overlap).
// 512 threads = 8 waves (2M x 4N), wave tile 64x32, one barrier per k-tile.
// LDS: 2buf x {ARe,AIm} x 128 x 16 + same for B = 32 KB, + params ~8 KB.
// ---------------------------------------------------------------------------
__global__ __launch_bounds__(512) void ewald_fused(
    const float* __restrict__ theta, const float* __restrict__ reA,
    const float* __restrict__ imA, const float* __restrict__ x0A,
    const float* __restrict__ y0A, const float* __restrict__ lsA,
    const float* __restrict__ X, const float* __restrict__ Y,
    float* __restrict__ out)
{
    __shared__ f16 smA[2][2][BM][BK];   // [buf][Re/Im][row][k]
    __shared__ f16 smB[2][2][BN][BK];
    __shared__ float skx[NB], sky[NB], sre[NB], sim[NB],
                     spx[NB], spy[NB], sis2[NB];
    __shared__ float sX[BM], sY[BN];

    const int t    = threadIdx.x;
    const int lane = t & 63;
    const int wave = t >> 6;       // 0..7
    const int wm   = wave >> 2;    // 0..1 -> M offset 64
    const int wn   = wave & 3;     // 0..3 -> N offset 32
    const int la   = lane & 31;
    const int lg   = lane >> 5;

    // XCD-aware swizzle (256 blocks, 8 XCDs)
    const int flat = blockIdx.x;
    const int swz  = (flat & 7) * 32 + (flat >> 3);
    const int m0   = (swz >> 4) * BM;
    const int n0   = (swz & 15) * BN;

    // ---- prologue: per-beam params + axis coordinates into LDS ----
    if (t < 128) {
        sX[t] = X[(size_t)(m0 + t) * RES];   // X[i][0] = x_i (indexing='ij')
    } else if (t < 256) {
        sY[t - 128] = Y[n0 + (t - 128)];     // Y[0][j] = y_j
    } else {
        const int b = t - 256;
        float s, c;
        __sincosf(theta[b], &s, &c);
        skx[b] = 50.0f * c;
        sky[b] = 50.0f * s;
        const float sig = __expf(lsA[b]) + 0.001f;
        sis2[b] = 1.0f / (sig * sig);
        sre[b] = reA[b]; sim[b] = imA[b];
        spx[b] = x0A[b]; spy[b] = y0A[b];
    }
    __syncthreads();

    // ---- eval mapping: thread -> 2 beams (kk2, kk2+1) x 2 rows ----
    const int kk2 = (t & 7) * 2;   // beam pair within k-tile
    const int grp = t >> 3;        // 0..63 -> rows grp*2, grp*2+1

    // Evaluate k-tile kt (16 beams) into buffer bf. Each thread: 2 beams x
    // 2 rows x {A,B} = 8 sincos/exp evals; packed f16x2 (b32) LDS writes.
    #define EVAL(bf, kt)                                                      \
    do {                                                                      \
        const int b0_ = (kt) * BK + kk2;                                      \
        float aR_[2][2], aI_[2][2], bR_[2][2], bI_[2][2];                     \
        _Pragma("unroll")                                                     \
        for (int jb = 0; jb < 2; ++jb) {                                      \
            const int b_ = b0_ + jb;                                          \
            const float kx = skx[b_], ky = sky[b_];                           \
            const float re = sre[b_], im = sim[b_];                           \
            const float px = spx[b_], py = spy[b_];                           \
            const float is2 = sis2[b_];                                       \
            _Pragma("unroll")                                                 \
            for (int r = 0; r < 2; ++r) {                                     \
                const int row = grp * 2 + r;                                  \
                float s_, c_;                                                 \
                const float xv = sX[row];                                     \
                __sincosf(kx * xv, &s_, &c_);                                 \
                const float dx = xv - px;                                     \
                const float ex = __expf(-dx * dx * is2);                      \
                aR_[jb][r] = ex * (re * c_ - im * s_);                        \
                aI_[jb][r] = ex * (re * s_ + im * c_);                        \
                const float yv = sY[row];                                     \
                __sincosf(ky * yv, &s_, &c_);                                 \
                const float dy = yv - py;                                     \
                const float ey = __expf(-dy * dy * is2);                      \
                bR_[jb][r] = ey * c_;                                         \
                bI_[jb][r] = ey * s_;                                         \
            }                                                                 \
        }                                                                     \
        _Pragma("unroll")                                                     \
        for (int r = 0; r < 2; ++r) {                                         \
            const int row = grp * 2 + r;                                      \
            union { f16 h[2]; unsigned int u; } p_;                           \
            p_.h[0] = (f16)aR_[0][r]; p_.h[1] = (f16)aR_[1][r];               \
            *(unsigned int*)&smA[bf][0][row][kk2] = p_.u;                     \
            p_.h[0] = (f16)aI_[0][r]; p_.h[1] = (f16)aI_[1][r];               \
            *(unsigned int*)&smA[bf][1][row][kk2] = p_.u;                     \
            p_.h[0] = (f16)bR_[0][r]; p_.h[1] = (f16)bR_[1][r];               \
            *(unsigned int*)&smB[bf][0][row][kk2] = p_.u;                     \
            p_.h[0] = (f16)bI_[0][r]; p_.h[1] = (f16)bI_[1][r];               \
            *(unsigned int*)&smB[bf][1][row][kk2] = p_.u;                     \
        }                                                                     \
    } while (0)

    // ---- fragment LDS element-offsets (within a plane) ----
    const int offA0 = (wm * 64 +  0 + la) * BK + lg * 8;
    const int offA1 = (wm * 64 + 32 + la) * BK + lg * 8;
    const int offB  = (wn * 32 + la) * BK + lg * 8;

    f32x16 accRe0 = (f32x16)0.0f, accIm0 = (f32x16)0.0f;
    f32x16 accRe1 = (f32x16)0.0f, accIm1 = (f32x16)0.0f;

    // ---- k-tile 0 ----
    EVAL(0, 0);
    __syncthreads();

    for (int kt = 0; kt < NKT; ++kt) {
        const f16* sA = &smA[kt & 1][0][0][0];
        const f16* sB = &smB[kt & 1][0][0][0];
        const f16x8 aR0 = *(const f16x8*)(sA + offA0);
        const f16x8 aR1 = *(const f16x8*)(sA + offA1);
        const f16x8 aI0 = *(const f16x8*)(sA + PL + offA0);
        const f16x8 aI1 = *(const f16x8*)(sA + PL + offA1);
        const f16x8 bR  = *(const f16x8*)(sB + offB);
        const f16x8 bI  = *(const f16x8*)(sB + PL + offB);
        const f16x8 bN  = neg8(bI);

        // interleaved so no two consecutive MFMAs share an accumulator
        accRe0 = __builtin_amdgcn_mfma_f32_32x32x16_f16(aR0, bR, accRe0, 0, 0, 0);
        accIm0 = __builtin_amdgcn_mfma_f32_32x32x16_f16(aR0, bI, accIm0, 0, 0, 0);
        accRe1 = __builtin_amdgcn_mfma_f32_32x32x16_f16(aR1, bR, accRe1, 0, 0, 0);
        accIm1 = __builtin_amdgcn_mfma_f32_32x32x16_f16(aR1, bI, accIm1, 0, 0, 0);
        accRe0 = __builtin_amdgcn_mfma_f32_32x32x16_f16(aI0, bN, accRe0, 0, 0, 0);
        accIm0 = __builtin_amdgcn_mfma_f32_32x32x16_f16(aI0, bR, accIm0, 0, 0, 0);
        accRe1 = __builtin_amdgcn_mfma_f32_32x32x16_f16(aI1, bN, accRe1, 0, 0, 0);
        accIm1 = __builtin_amdgcn_mfma_f32_32x32x16_f16(aI1, bR, accIm1, 0, 0, 0);

        // evaluate next k-tile on the VALU while MFMA pipe drains
        if (kt + 1 < NKT)
            EVAL((kt + 1) & 1, kt + 1);

        __syncthreads();
    }

    // ---- epilogue: out = Re^2 + Im^2 ----
    // C/D layout (32x32): col = lane&31, row = (reg&3) + 8*(reg>>2) + 4*(lane>>5)
    const int gn     = n0 + wn * 32 + la;
    const int gmBase = m0 + wm * 64;
    #pragma unroll
    for (int r = 0; r < 16; ++r) {
        const int row = (r & 3) + 8 * (r >> 2) + 4 * lg;
        const float er = accRe0[r], ei = accIm0[r];
        out[(size_t)(gmBase + row) * RES + gn] = er * er + ei * ei;
    }
    #pragma unroll
    for (int r = 0; r < 16; ++r) {
        const int row = (r & 3) + 8 * (r >> 2) + 4 * lg;
        const float er = accRe1[r], ei = accIm1[r];
        out[(size_t)(gmBase + 32 + row) * RES + gn] = er * er + ei * ei;
    }
    #undef EVAL
}

// ---------------------------------------------------------------------------
extern "C" void kernel_launch(void* const* d_in, const int* in_sizes, int n_in,
                              void* d_out, int out_size, void* d_ws, size_t ws_size,
                              hipStream_t stream) {
    const float* theta = (const float*)d_in[0];
    const float* reA   = (const float*)d_in[1];
    const float* imA   = (const float*)d_in[2];
    const float* x0A   = (const float*)d_in[3];
    const float* y0A   = (const float*)d_in[4];
    const float* lsA   = (const float*)d_in[5];
    const float* X     = (const float*)d_in[6];
    const float* Y     = (const float*)d_in[7];
    float* out = (float*)d_out;

    ewald_fused<<<256, 512, 0, stream>>>(theta, reA, imA, x0A, y0A, lsA,
                                         X, Y, out);
}